// Round 8
// baseline (390.608 us; speedup 1.0000x reference)
//
#include <hip/hip_runtime.h>
#include <hip/hip_bf16.h>
#include <stdint.h>

#define B_ 16
#define N_ 2048
#define D_ 128

typedef __bf16 bf16_t;
typedef bf16_t bf16x8 __attribute__((ext_vector_type(8)));
typedef float f32x4 __attribute__((ext_vector_type(4)));

// ---------------- K1: emb GEMM + fused q/k/exps + adj-pack + ws zeroing ------
// Pb[b][d][n] = bf16( sum_k x[b][n][k]*W[d][k] + be[d] )
// Also: packs adj rows [flat*4, flat*4+4) into bitmask, zeroes denom+counters.
__global__ __launch_bounds__(256, 2) void k_emb(const float* __restrict__ x,
                                                const float* __restrict__ W,
                                                const float* __restrict__ adj,
                                                const float* __restrict__ be,
                                                const float* __restrict__ wq,
                                                const float* __restrict__ bq,
                                                const float* __restrict__ wk,
                                                const float* __restrict__ bk,
                                                bf16_t* __restrict__ Pb,
                                                float* __restrict__ qa, float* __restrict__ ka,
                                                float* __restrict__ Eq, float* __restrict__ eqs,
                                                float* __restrict__ Ek, float* __restrict__ eks,
                                                unsigned int* __restrict__ bits,
                                                float* __restrict__ denom,
                                                int* __restrict__ counters) {
    __shared__ float xs[32][68];     // [k][n]  64n + pad
    __shared__ float ws[32][132];    // [k][d]  128d + pad
    __shared__ float qs[64], ks[64];
    int b  = blockIdx.y;
    int n0 = blockIdx.x * 64;
    int flat = b * 32 + blockIdx.x;     // 0..511
    int tid = threadIdx.x;
    int tx = tid & 15, ty = tid >> 4;   // tx: n-dir (4 n), ty: d-dir (8 d)
    if (tid < 64) { qs[tid] = 0.f; ks[tid] = 0.f; }

    float acc[4][8] = {};               // [n][d]
    f32x4 xr[2], wr[4];

    auto loadregs = [&](int kc) {
#pragma unroll
        for (int s = 0; s < 2; ++s) {
            int p = tid + 256 * s;
            int n = p >> 3, kq = p & 7;
            xr[s] = *(const f32x4*)(x + ((size_t)(b * N_ + n0 + n)) * D_ + kc * 32 + kq * 4);
        }
#pragma unroll
        for (int s = 0; s < 4; ++s) {
            int p = tid + 256 * s;
            int d = p >> 3, kq = p & 7;
            wr[s] = *(const f32x4*)(W + (size_t)d * D_ + kc * 32 + kq * 4);
        }
    };
    auto writelds = [&]() {
#pragma unroll
        for (int s = 0; s < 2; ++s) {
            int p = tid + 256 * s;
            int n = p >> 3, kq = p & 7;
#pragma unroll
            for (int u = 0; u < 4; ++u) xs[kq * 4 + u][n] = xr[s][u];
        }
#pragma unroll
        for (int s = 0; s < 4; ++s) {
            int p = tid + 256 * s;
            int d = p >> 3, kq = p & 7;
#pragma unroll
            for (int u = 0; u < 4; ++u) ws[kq * 4 + u][d] = wr[s][u];
        }
    };

    loadregs(0);

    // ---- fused: pack 4 adj rows (thread: row flat*4+(tid>>6), word tid&63) ----
    {
        int prow  = flat * 4 + (tid >> 6);
        int pword = tid & 63;
        const float* ap = adj + (size_t)prow * N_ + pword * 32;
        unsigned int m = 0;
#pragma unroll
        for (int g = 0; g < 8; ++g) {
            f32x4 v = *(const f32x4*)(ap + g * 4);
#pragma unroll
            for (int u = 0; u < 4; ++u)
                m |= (v[u] > 0.5f ? 1u : 0u) << (g * 4 + u);
        }
        bits[prow * 64 + pword] = m;
    }
    // ---- fused: zero denom + counters ----
    if (tid < 64) denom[flat * 64 + tid] = 0.f;
    if (tid == 64 && flat < 128) counters[flat] = 0;

    for (int kc = 0; kc < 4; ++kc) {
        writelds();
        __syncthreads();
        if (kc < 3) loadregs(kc + 1);
#pragma unroll 4
        for (int k = 0; k < 32; ++k) {
            f32x4 xv  = *(const f32x4*)&xs[k][tx * 4];
            f32x4 wv0 = *(const f32x4*)&ws[k][ty * 8];
            f32x4 wv1 = *(const f32x4*)&ws[k][ty * 8 + 4];
#pragma unroll
            for (int i = 0; i < 4; ++i)
#pragma unroll
                for (int j = 0; j < 8; ++j)
                    acc[i][j] += xv[i] * ((j < 4) ? wv0[j] : wv1[j - 4]);
        }
        __syncthreads();
    }

    float qp[4] = {}, kp[4] = {};
#pragma unroll
    for (int j = 0; j < 8; ++j) {
        int d = ty * 8 + j;
        float bj  = be[d];
        float wqj = wq[d];
        float wkj = wk[d];
        f32x4 o;
        bf16_t ob[4];
#pragma unroll
        for (int i = 0; i < 4; ++i) {
            o[i] = acc[i][j] + bj;
            qp[i] += o[i] * wqj;
            kp[i] += o[i] * wkj;
            ob[i] = (bf16_t)o[i];
        }
        *(uint2*)(Pb + ((size_t)b * D_ + d) * N_ + n0 + tx * 4) = *(uint2*)ob;
    }
#pragma unroll
    for (int i = 0; i < 4; ++i) {
        atomicAdd(&qs[tx * 4 + i], qp[i]);
        atomicAdd(&ks[tx * 4 + i], kp[i]);
    }
    __syncthreads();
    if (tid < 64) {
        int idx = b * N_ + n0 + tid;
        float aq = qs[tid] + bq[0];
        float ak = ks[tid] + bk[0];
        qa[idx] = aq;          ka[idx] = ak;
        Eq[idx] = expf(aq);    eqs[idx] = expf(0.01f * aq);
        Ek[idx] = expf(ak);    eks[idx] = expf(0.01f * ak);
    }
}

// ---------------- K2: denom[b][j] = sum_i V(b,i,j)  + last-block finalize ----
__global__ __launch_bounds__(256) void k_denom(const unsigned int* __restrict__ bits,
                                               const float* __restrict__ qa,
                                               const float* __restrict__ ka,
                                               const float* __restrict__ Eq,
                                               const float* __restrict__ eqs,
                                               const float* __restrict__ Ek,
                                               const float* __restrict__ eks,
                                               float* __restrict__ denom,
                                               int* __restrict__ counters,
                                               float* __restrict__ rd,
                                               float* __restrict__ Eqr,
                                               float* __restrict__ eqr) {
    __shared__ int lastFlag;
    int jt  = blockIdx.x;     // 0..7
    int b   = blockIdx.y;     // 0..15
    int seg = blockIdx.z;     // 0..7
    int j = jt * 256 + threadIdx.x;
    float qj  = qa[b * N_ + j];
    float Eqj = Eq[b * N_ + j];
    float eqj = eqs[b * N_ + j];
    int shift = j & 31;
    int wid   = j >> 5;
    float acc = 0.f;
    int i0 = seg * 256;
#pragma unroll 16
    for (int i = i0; i < i0 + 256; ++i) {
        float kk  = ka[b * N_ + i];
        float Ekk = Ek[b * N_ + i];
        float ekk = eks[b * N_ + i];
        unsigned int w = bits[i * 64 + wid];
        float z  = kk + qj;
        float f1 = z > 0.f ? Ekk : ekk;
        float f2 = z > 0.f ? Eqj : eqj;
        float v  = f1 * f2;
        acc += ((w >> shift) & 1u) ? v : 1.0f;
    }
    atomicAdd(&denom[b * N_ + j], acc);
    __threadfence();
    if (threadIdx.x == 0) {
        int old = atomicAdd(&counters[b * 8 + jt], 1);
        lastFlag = (old == 7);
    }
    __syncthreads();
    if (lastFlag) {
        __threadfence();
        int idx = b * N_ + j;
        float dn = atomicAdd(&denom[idx], 0.0f);   // device-coherent read
        float r = 1.0f / dn;
        rd[idx]  = r;
        Eqr[idx] = Eqj * r;
        eqr[idx] = eqj * r;
    }
}

// ---------------- K3: vals = A' @ P  (barrier-light, B direct from global) ---
// A'[i,j] = edge ? (z>0?Ek_i:ek_i)*(z>0?Eqr_j:eqr_j) : rd_j
// Block 64i x 128d, 4 waves (ig = w&1 -> 32i, dg = w>>1 -> 64d).
// Per step (64 j): B-frags read from GLOBAL into parity regs one step ahead;
// j-side streams parity-pipelined; A(s+1) generated at step s (dedup: wave
// makes only hh=dg, exchanges other half via 16KB dbuf ldsA). Exactly ONE
// lgkm-only s_barrier per step — vmcnt never drained.
__global__ __launch_bounds__(256, 2) void k_attn(const float* __restrict__ qa,
                                                 const float* __restrict__ ka,
                                                 const float* __restrict__ Ek,
                                                 const float* __restrict__ eks,
                                                 const float* __restrict__ rd,
                                                 const float* __restrict__ Eqr,
                                                 const float* __restrict__ eqr,
                                                 const unsigned int* __restrict__ bits,
                                                 const bf16_t* __restrict__ Pb,
                                                 float* __restrict__ out) {
    __shared__ __align__(16) bf16_t ldsA[2 * 4 * 2 * 64 * 8];   // 16 KB
    int b     = blockIdx.y;
    int ibase = blockIdx.x * 64;
    int tid   = threadIdx.x;
    int w     = tid >> 6;
    int lane  = tid & 63;
    int m16   = lane & 15;
    int quad  = lane >> 4;
    int ig    = w & 1;
    int dg    = w >> 1;

    int iA = ibase + 2 * ig * 16 + m16;
    int iB = iA + 16;
    float mk0 = -ka[b * N_ + iA], mk1 = -ka[b * N_ + iB];
    float Ek0 = Ek[b * N_ + iA],  Ek1 = Ek[b * N_ + iB];
    float ek0 = eks[b * N_ + iA], ek1 = eks[b * N_ + iB];
    const unsigned int* brA = bits + (size_t)iA * 64;
    const unsigned int* brB = bits + (size_t)iB * 64;
    const float* qp = qa  + b * N_;
    const float* Ep = Eqr + b * N_;
    const float* ep = eqr + b * N_;
    const float* rp = rd  + b * N_;
    const bf16_t* PtB = Pb + (size_t)b * D_ * N_;

    f32x4 acc[2][4];
#pragma unroll
    for (int c = 0; c < 2; ++c)
#pragma unroll
        for (int nt = 0; nt < 4; ++nt) acc[c][nt] = (f32x4){0.f, 0.f, 0.f, 0.f};

    // pipeline registers
    f32x4 jq[2][2], jE[2][2], je[2][2], jr[2][2];
    unsigned int mA[2], mB[2];
    bf16x8 Bv[2][8];        // [slot][h2*4+nt]
    bf16x8 aOwn[2][2];      // [slot][chunk]

    // byte offset into ldsA
    auto AOFF = [&](int par, int chunk, int hh, int ln) {
        return (((par * 4 + chunk) * 2 + hh) * 64 + ln) * 16;
    };

    auto ldj = [&](int sl, int jb) {
        int j0 = jb + dg * 32 + quad * 8;
        jq[sl][0] = *(const f32x4*)(qp + j0);  jq[sl][1] = *(const f32x4*)(qp + j0 + 4);
        jE[sl][0] = *(const f32x4*)(Ep + j0);  jE[sl][1] = *(const f32x4*)(Ep + j0 + 4);
        je[sl][0] = *(const f32x4*)(ep + j0);  je[sl][1] = *(const f32x4*)(ep + j0 + 4);
        jr[sl][0] = *(const f32x4*)(rp + j0);  jr[sl][1] = *(const f32x4*)(rp + j0 + 4);
        mA[sl] = brA[(jb >> 5) + dg];
        mB[sl] = brB[(jb >> 5) + dg];
    };

    auto ldB = [&](int sl, int jb) {
#pragma unroll
        for (int h2 = 0; h2 < 2; ++h2)
#pragma unroll
            for (int nt = 0; nt < 4; ++nt)
                Bv[sl][h2 * 4 + nt] = *(const bf16x8*)(
                    PtB + (size_t)(dg * 64 + nt * 16 + m16) * N_ + jb + h2 * 32 + quad * 8);
    };

    // generate own-hh A-frags for both i-chunks from jregs[src] -> aOwn[dst]+ldsA[dst]
    auto genA = [&](int src, int dst) {
        bf16x8 fA, fB;
#pragma unroll
        for (int t = 0; t < 8; ++t) {
            float qv = (t < 4) ? jq[src][0][t] : jq[src][1][t - 4];
            float Er = (t < 4) ? jE[src][0][t] : jE[src][1][t - 4];
            float er = (t < 4) ? je[src][0][t] : je[src][1][t - 4];
            float rj = (t < 4) ? jr[src][0][t] : jr[src][1][t - 4];
            int bit = quad * 8 + t;
            {
                bool c = qv > mk0;
                float v = (c ? Ek0 : ek0) * (c ? Er : er);
                fA[t] = (bf16_t)(((mA[src] >> bit) & 1u) ? v : rj);
            }
            {
                bool c = qv > mk1;
                float v = (c ? Ek1 : ek1) * (c ? Er : er);
                fB[t] = (bf16_t)(((mB[src] >> bit) & 1u) ? v : rj);
            }
        }
        aOwn[dst][0] = fA;
        aOwn[dst][1] = fB;
        *(bf16x8*)((char*)ldsA + AOFF(dst, 2 * ig + 0, dg, lane)) = fA;
        *(bf16x8*)((char*)ldsA + AOFF(dst, 2 * ig + 1, dg, lane)) = fB;
    };

    // ---- preamble ----
    ldj(0, 0);         // for A(0)
    ldj(1, 64);        // for A(1), consumed at step 0
    ldB(1, 0);         // B for step 0
    genA(0, 1);        // A(0) -> slot 1
    __syncthreads();

#pragma unroll 1
    for (int s2 = 0; s2 < N_ / 128; ++s2) {
#pragma unroll
        for (int par = 0; par < 2; ++par) {
            int step = s2 * 2 + par;
            if (step <= 29) ldj(par, (step + 2) * 64);
            if (step <= 30) ldB(par, (step + 1) * 64);
            if (step <= 30) genA(par ^ 1, par);

            int src = par ^ 1;
            bf16x8 o0 = *(const bf16x8*)((char*)ldsA + AOFF(src, 2 * ig + 0, 1 - dg, lane));
            bf16x8 o1 = *(const bf16x8*)((char*)ldsA + AOFF(src, 2 * ig + 1, 1 - dg, lane));
#pragma unroll
            for (int nt = 0; nt < 4; ++nt) {
                acc[0][nt] = __builtin_amdgcn_mfma_f32_16x16x32_bf16(aOwn[src][0], Bv[src][dg * 4 + nt], acc[0][nt], 0, 0, 0);
                acc[1][nt] = __builtin_amdgcn_mfma_f32_16x16x32_bf16(aOwn[src][1], Bv[src][dg * 4 + nt], acc[1][nt], 0, 0, 0);
                acc[0][nt] = __builtin_amdgcn_mfma_f32_16x16x32_bf16(o0, Bv[src][(1 - dg) * 4 + nt], acc[0][nt], 0, 0, 0);
                acc[1][nt] = __builtin_amdgcn_mfma_f32_16x16x32_bf16(o1, Bv[src][(1 - dg) * 4 + nt], acc[1][nt], 0, 0, 0);
            }
            if (step <= 30)
                asm volatile("s_waitcnt lgkmcnt(0)\n\ts_barrier" ::: "memory");
        }
    }

    // ---- epilogue: C layout col=lane&15 (d), row=quad*4+r (i) ----
#pragma unroll
    for (int c = 0; c < 2; ++c) {
        int irow = ibase + (2 * ig + c) * 16 + quad * 4;
#pragma unroll
        for (int nt = 0; nt < 4; ++nt) {
            int d = dg * 64 + nt * 16 + m16;
#pragma unroll
            for (int r = 0; r < 4; ++r)
                out[((size_t)b * N_ + irow + r) * D_ + d] = acc[c][nt][r];
        }
    }
}

extern "C" void kernel_launch(void* const* d_in, const int* in_sizes, int n_in,
                              void* d_out, int out_size, void* d_ws, size_t ws_size,
                              hipStream_t stream) {
    const float* x   = (const float*)d_in[0];
    const float* adj = (const float*)d_in[1];
    const float* W   = (const float*)d_in[2];
    const float* be  = (const float*)d_in[3];
    const float* wq  = (const float*)d_in[4];
    const float* bq  = (const float*)d_in[5];
    const float* wk  = (const float*)d_in[6];
    const float* bk  = (const float*)d_in[7];
    float* out = (float*)d_out;

    char* ws = (char*)d_ws;
    size_t off = 0;
    bf16_t* Pb = (bf16_t*)(ws + off); off += (size_t)B_ * D_ * N_ * 2;   // 8 MB
    float* qa  = (float*)(ws + off);  off += (size_t)B_ * N_ * 4;
    float* ka  = (float*)(ws + off);  off += (size_t)B_ * N_ * 4;
    float* denom = (float*)(ws + off); off += (size_t)B_ * N_ * 4;
    float* Eq  = (float*)(ws + off);  off += (size_t)B_ * N_ * 4;
    float* eqs = (float*)(ws + off);  off += (size_t)B_ * N_ * 4;
    float* Ek  = (float*)(ws + off);  off += (size_t)B_ * N_ * 4;
    float* eks = (float*)(ws + off);  off += (size_t)B_ * N_ * 4;
    float* rd  = (float*)(ws + off);  off += (size_t)B_ * N_ * 4;
    float* Eqr = (float*)(ws + off);  off += (size_t)B_ * N_ * 4;
    float* eqr = (float*)(ws + off);  off += (size_t)B_ * N_ * 4;
    unsigned int* bits = (unsigned int*)(ws + off); off += (size_t)N_ * 64 * 4; // 512 KB
    int* counters = (int*)(ws + off); off += 128 * 4;

    k_emb<<<dim3(N_ / 64, B_), 256, 0, stream>>>(x, W, adj, be, wq, bq, wk, bk,
                                                 Pb, qa, ka, Eq, eqs, Ek, eks,
                                                 bits, denom, counters);
    k_denom<<<dim3(8, 16, 8), 256, 0, stream>>>(bits, qa, ka, Eq, eqs, Ek, eks,
                                                denom, counters, rd, Eqr, eqr);
    k_attn<<<dim3(N_ / 64, B_), 256, 0, stream>>>(qa, ka, Ek, eks, rd, Eqr, eqr,
                                                  bits, Pb, out);
}

// Round 9
// 200.270 us; speedup vs baseline: 1.9504x; 1.9504x over previous
//
#include <hip/hip_runtime.h>
#include <hip/hip_bf16.h>
#include <stdint.h>

#define B_ 16
#define N_ 2048
#define D_ 128

typedef __bf16 bf16_t;
typedef bf16_t bf16x8 __attribute__((ext_vector_type(8)));
typedef float f32x4 __attribute__((ext_vector_type(4)));

// ---------------- K1: emb GEMM + fused q/k/exps + adj-pack + denom zero ------
// Pb[b][d][n] = bf16( sum_k x[b][n][k]*W[d][k] + be[d] )
__global__ __launch_bounds__(256, 2) void k_emb(const float* __restrict__ x,
                                                const float* __restrict__ W,
                                                const float* __restrict__ adj,
                                                const float* __restrict__ be,
                                                const float* __restrict__ wq,
                                                const float* __restrict__ bq,
                                                const float* __restrict__ wk,
                                                const float* __restrict__ bk,
                                                bf16_t* __restrict__ Pb,
                                                float* __restrict__ qa, float* __restrict__ ka,
                                                float* __restrict__ Eq, float* __restrict__ eqs,
                                                float* __restrict__ Ek, float* __restrict__ eks,
                                                unsigned int* __restrict__ bits,
                                                float* __restrict__ denom) {
    __shared__ float xs[32][68];     // [k][n]  64n + pad
    __shared__ float ws[32][132];    // [k][d]  128d + pad
    __shared__ float qs[64], ks[64];
    int b  = blockIdx.y;
    int n0 = blockIdx.x * 64;
    int flat = b * 32 + blockIdx.x;     // 0..511
    int tid = threadIdx.x;
    int tx = tid & 15, ty = tid >> 4;   // tx: n-dir (4 n), ty: d-dir (8 d)
    if (tid < 64) { qs[tid] = 0.f; ks[tid] = 0.f; }

    float acc[4][8] = {};               // [n][d]
    f32x4 xr[2], wr[4];

    auto loadregs = [&](int kc) {
#pragma unroll
        for (int s = 0; s < 2; ++s) {
            int p = tid + 256 * s;
            int n = p >> 3, kq = p & 7;
            xr[s] = *(const f32x4*)(x + ((size_t)(b * N_ + n0 + n)) * D_ + kc * 32 + kq * 4);
        }
#pragma unroll
        for (int s = 0; s < 4; ++s) {
            int p = tid + 256 * s;
            int d = p >> 3, kq = p & 7;
            wr[s] = *(const f32x4*)(W + (size_t)d * D_ + kc * 32 + kq * 4);
        }
    };
    auto writelds = [&]() {
#pragma unroll
        for (int s = 0; s < 2; ++s) {
            int p = tid + 256 * s;
            int n = p >> 3, kq = p & 7;
#pragma unroll
            for (int u = 0; u < 4; ++u) xs[kq * 4 + u][n] = xr[s][u];
        }
#pragma unroll
        for (int s = 0; s < 4; ++s) {
            int p = tid + 256 * s;
            int d = p >> 3, kq = p & 7;
#pragma unroll
            for (int u = 0; u < 4; ++u) ws[kq * 4 + u][d] = wr[s][u];
        }
    };

    loadregs(0);

    // ---- fused: pack 4 adj rows (thread: row flat*4+(tid>>6), word tid&63) ----
    {
        int prow  = flat * 4 + (tid >> 6);
        int pword = tid & 63;
        const float* ap = adj + (size_t)prow * N_ + pword * 32;
        unsigned int m = 0;
#pragma unroll
        for (int g = 0; g < 8; ++g) {
            f32x4 v = *(const f32x4*)(ap + g * 4);
#pragma unroll
            for (int u = 0; u < 4; ++u)
                m |= (v[u] > 0.5f ? 1u : 0u) << (g * 4 + u);
        }
        bits[prow * 64 + pword] = m;
    }
    // ---- fused: zero denom ----
    if (tid < 64) denom[flat * 64 + tid] = 0.f;

    for (int kc = 0; kc < 4; ++kc) {
        writelds();
        __syncthreads();
        if (kc < 3) loadregs(kc + 1);
#pragma unroll 4
        for (int k = 0; k < 32; ++k) {
            f32x4 xv  = *(const f32x4*)&xs[k][tx * 4];
            f32x4 wv0 = *(const f32x4*)&ws[k][ty * 8];
            f32x4 wv1 = *(const f32x4*)&ws[k][ty * 8 + 4];
#pragma unroll
            for (int i = 0; i < 4; ++i)
#pragma unroll
                for (int j = 0; j < 8; ++j)
                    acc[i][j] += xv[i] * ((j < 4) ? wv0[j] : wv1[j - 4]);
        }
        __syncthreads();
    }

    float qp[4] = {}, kp[4] = {};
#pragma unroll
    for (int j = 0; j < 8; ++j) {
        int d = ty * 8 + j;
        float bj  = be[d];
        float wqj = wq[d];
        float wkj = wk[d];
        f32x4 o;
        bf16_t ob[4];
#pragma unroll
        for (int i = 0; i < 4; ++i) {
            o[i] = acc[i][j] + bj;
            qp[i] += o[i] * wqj;
            kp[i] += o[i] * wkj;
            ob[i] = (bf16_t)o[i];
        }
        *(uint2*)(Pb + ((size_t)b * D_ + d) * N_ + n0 + tx * 4) = *(uint2*)ob;
    }
#pragma unroll
    for (int i = 0; i < 4; ++i) {
        atomicAdd(&qs[tx * 4 + i], qp[i]);
        atomicAdd(&ks[tx * 4 + i], kp[i]);
    }
    __syncthreads();
    if (tid < 64) {
        int idx = b * N_ + n0 + tid;
        float aq = qs[tid] + bq[0];
        float ak = ks[tid] + bk[0];
        qa[idx] = aq;          ka[idx] = ak;
        Eq[idx] = expf(aq);    eqs[idx] = expf(0.01f * aq);
        Ek[idx] = expf(ak);    eks[idx] = expf(0.01f * ak);
    }
}

// ---------------- K2: denom[b][j] = sum_i V(b,i,j) ---------------------------
__global__ __launch_bounds__(256) void k_denom(const unsigned int* __restrict__ bits,
                                               const float* __restrict__ qa,
                                               const float* __restrict__ ka,
                                               const float* __restrict__ Eq,
                                               const float* __restrict__ eqs,
                                               const float* __restrict__ Ek,
                                               const float* __restrict__ eks,
                                               float* __restrict__ denom) {
    int jt  = blockIdx.x;     // 0..7
    int b   = blockIdx.y;     // 0..15
    int seg = blockIdx.z;     // 0..7
    int j = jt * 256 + threadIdx.x;
    float qj  = qa[b * N_ + j];
    float Eqj = Eq[b * N_ + j];
    float eqj = eqs[b * N_ + j];
    int shift = j & 31;
    int wid   = j >> 5;
    float acc = 0.f;
    int i0 = seg * 256;
#pragma unroll 16
    for (int i = i0; i < i0 + 256; ++i) {
        float kk  = ka[b * N_ + i];
        float Ekk = Ek[b * N_ + i];
        float ekk = eks[b * N_ + i];
        unsigned int w = bits[i * 64 + wid];
        float z  = kk + qj;
        float f1 = z > 0.f ? Ekk : ekk;
        float f2 = z > 0.f ? Eqj : eqj;
        float v  = f1 * f2;
        acc += ((w >> shift) & 1u) ? v : 1.0f;
    }
    atomicAdd(&denom[b * N_ + j], acc);
}

// ---------------- K2b: rd = 1/denom; Eqr = Eq*rd; eqr = eqs*rd ---------------
__global__ __launch_bounds__(256) void k_post(const float* __restrict__ denom,
                                              const float* __restrict__ Eq,
                                              const float* __restrict__ eqs,
                                              float* __restrict__ rd,
                                              float* __restrict__ Eqr,
                                              float* __restrict__ eqr) {
    int t = blockIdx.x * 256 + threadIdx.x;   // over B*N
    float r = 1.0f / denom[t];
    rd[t]  = r;
    Eqr[t] = Eq[t] * r;
    eqr[t] = eqs[t] * r;
}

// ---------------- K3: vals = A' @ P ------------------------------------------
// A'[i,j] = edge ? (z>0?Ek_i:ek_i)*(z>0?Eqr_j:eqr_j) : rd_j
// Block 32i x 128d, 4 waves (ig = w&1 -> one 16i chunk, dg = w>>1 -> 64d, also
// the j-half this wave generates A for). Grid 1024 -> up to 4 blocks/CU to
// de-phase barrier convoys. B staged in LDS dbuf via global_load_lds w=16
// (XOR swizzle); A exchanged via 4KB ldsA + raw lgkm-only barrier (B prefetch
// vmcnt stays in flight); j-side inputs register-pipelined one step ahead.
// Sign test: z>0 <=> Eqr_j > rcp(Ek_i)*rd_j (leaky-relu continuous at 0, so
// boundary flips are rounding-level).
__global__ __launch_bounds__(256, 4) void k_attn(const float* __restrict__ Ek,
                                                 const float* __restrict__ eks,
                                                 const float* __restrict__ rd,
                                                 const float* __restrict__ Eqr,
                                                 const float* __restrict__ eqr,
                                                 const unsigned int* __restrict__ bits,
                                                 const bf16_t* __restrict__ Pb,
                                                 float* __restrict__ out) {
    __shared__ __align__(16) bf16_t ldsB[2][128 * 64];    // 32 KB, B dbuf
    __shared__ __align__(16) bf16_t ldsA[2 * 2 * 64 * 8]; // 4 KB: [chunk][half][lane]
    int b     = blockIdx.y;
    int ibase = blockIdx.x * 32;
    int tid   = threadIdx.x;
    int w     = tid >> 6;
    int lane  = tid & 63;
    int m16   = lane & 15;
    int quad  = lane >> 4;
    int ig    = w & 1;             // my 16i chunk
    int dg    = w >> 1;            // my 64d group; also my j-half

    int iR = ibase + ig * 16 + m16;
    float EkR = Ek[b * N_ + iR];
    float ekR = eks[b * N_ + iR];
    float TR  = __builtin_amdgcn_rcpf(EkR);   // z>0 <=> Eqr_j > TR*rd_j
    const unsigned int* br = bits + (size_t)iR * 64;
    const float* Ep = Eqr + b * N_;
    const float* ep = eqr + b * N_;
    const float* rp = rd  + b * N_;
    const bf16_t* PtB = Pb + (size_t)b * D_ * N_;

    f32x4 acc[4];
#pragma unroll
    for (int nt = 0; nt < 4; ++nt) acc[nt] = (f32x4){0.f, 0.f, 0.f, 0.f};

    // pipeline registers (own j-half only): E,e,r = 6 f32x4 per slot
    f32x4 jE[2][2], je[2][2], jr[2][2];
    unsigned int msk[2];

    auto ldj = [&](int sl, int jb) {
        int j0 = jb + dg * 32 + quad * 8;
        jE[sl][0] = *(const f32x4*)(Ep + j0);  jE[sl][1] = *(const f32x4*)(Ep + j0 + 4);
        je[sl][0] = *(const f32x4*)(ep + j0);  je[sl][1] = *(const f32x4*)(ep + j0 + 4);
        jr[sl][0] = *(const f32x4*)(rp + j0);  jr[sl][1] = *(const f32x4*)(rp + j0 + 4);
        msk[sl] = br[(jb >> 5) + dg];
    };

    // Stage 128d x 64j bf16 tile (16 KB), XOR swizzle on the GLOBAL address.
    auto stage = [&](int bufi, int jb) {
#pragma unroll
        for (int t = 0; t < 4; ++t) {
            int off = t * 4096 + tid * 16;               // byte offset in tile
            int d   = off >> 7;                          // row (128 B = 64 j)
            int g   = ((off & 127) >> 4) ^ (d & 7);      // swizzled j-chunk
            const bf16_t* gp = PtB + (size_t)d * N_ + jb + g * 8;
            __builtin_amdgcn_global_load_lds(
                (const __attribute__((address_space(1))) void*)gp,
                (__attribute__((address_space(3))) void*)((char*)(&ldsB[bufi][0]) + off),
                16, 0, 0);
        }
    };

    stage(0, 0);
    ldj(0, 0);
    __syncthreads();                 // drain initial stage + step-0 regs
    int buf = 0;
#pragma unroll 1
    for (int s2 = 0; s2 < N_ / 128; ++s2) {
#pragma unroll
        for (int par = 0; par < 2; ++par) {
            int step = s2 * 2 + par;
            int jb = step * 64;
            if (step + 1 < N_ / 64) {
                ldj(par ^ 1, jb + 64);       // j-side regs for next step
                stage(buf ^ 1, jb + 64);     // B prefetch for next step
            }

            // ---- A-gen: own (chunk ig, half dg) from registers ----
            bf16x8 af;
#pragma unroll
            for (int t = 0; t < 8; ++t) {
                float Er = (t < 4) ? jE[par][0][t] : jE[par][1][t - 4];
                float er = (t < 4) ? je[par][0][t] : je[par][1][t - 4];
                float rj = (t < 4) ? jr[par][0][t] : jr[par][1][t - 4];
                bool c = Er > TR * rj;
                float v = (c ? EkR : ekR) * (c ? Er : er);
                af[t] = (bf16_t)(((msk[par] >> (quad * 8 + t)) & 1u) ? v : rj);
            }
            *(bf16x8*)((char*)ldsA + (((ig * 2 + dg) * 64 + lane) * 16)) = af;

            // raw barrier: drain LDS only — B prefetch (vmcnt) stays in flight
            asm volatile("s_waitcnt lgkmcnt(0)\n\ts_barrier" ::: "memory");

            // ---- MFMA: own half from regs, other half from ldsA ----
            {
                int cph = ((dg * 4 + quad) ^ (m16 & 7)) * 8;
#pragma unroll
                for (int nt = 0; nt < 4; ++nt) {
                    int d = dg * 64 + nt * 16 + m16;
                    bf16x8 bf = *(const bf16x8*)&ldsB[buf][d * 64 + cph];
                    acc[nt] = __builtin_amdgcn_mfma_f32_16x16x32_bf16(af, bf, acc[nt], 0, 0, 0);
                }
            }
            {
                int oh = 1 - dg;
                bf16x8 ao = *(const bf16x8*)((char*)ldsA + (((ig * 2 + oh) * 64 + lane) * 16));
                int cph = ((oh * 4 + quad) ^ (m16 & 7)) * 8;
#pragma unroll
                for (int nt = 0; nt < 4; ++nt) {
                    int d = dg * 64 + nt * 16 + m16;
                    bf16x8 bf = *(const bf16x8*)&ldsB[buf][d * 64 + cph];
                    acc[nt] = __builtin_amdgcn_mfma_f32_16x16x32_bf16(ao, bf, acc[nt], 0, 0, 0);
                }
            }
            __syncthreads();   // drains next-step prefetch + guards lds reuse
            buf ^= 1;
        }
    }

    // ---- epilogue: C layout col=lane&15 (d), row=quad*4+r (i) ----
    int irow = ibase + ig * 16 + quad * 4;
#pragma unroll
    for (int nt = 0; nt < 4; ++nt) {
        int d = dg * 64 + nt * 16 + m16;
#pragma unroll
        for (int r = 0; r < 4; ++r)
            out[((size_t)b * N_ + irow + r) * D_ + d] = acc[nt][r];
    }
}

extern "C" void kernel_launch(void* const* d_in, const int* in_sizes, int n_in,
                              void* d_out, int out_size, void* d_ws, size_t ws_size,
                              hipStream_t stream) {
    const float* x   = (const float*)d_in[0];
    const float* adj = (const float*)d_in[1];
    const float* W   = (const float*)d_in[2];
    const float* be  = (const float*)d_in[3];
    const float* wq  = (const float*)d_in[4];
    const float* bq  = (const float*)d_in[5];
    const float* wk  = (const float*)d_in[6];
    const float* bk  = (const float*)d_in[7];
    float* out = (float*)d_out;

    char* ws = (char*)d_ws;
    size_t off = 0;
    bf16_t* Pb = (bf16_t*)(ws + off); off += (size_t)B_ * D_ * N_ * 2;   // 8 MB
    float* qa  = (float*)(ws + off);  off += (size_t)B_ * N_ * 4;
    float* ka  = (float*)(ws + off);  off += (size_t)B_ * N_ * 4;
    float* denom = (float*)(ws + off); off += (size_t)B_ * N_ * 4;
    float* Eq  = (float*)(ws + off);  off += (size_t)B_ * N_ * 4;
    float* eqs = (float*)(ws + off);  off += (size_t)B_ * N_ * 4;
    float* Ek  = (float*)(ws + off);  off += (size_t)B_ * N_ * 4;
    float* eks = (float*)(ws + off);  off += (size_t)B_ * N_ * 4;
    float* rd  = (float*)(ws + off);  off += (size_t)B_ * N_ * 4;
    float* Eqr = (float*)(ws + off);  off += (size_t)B_ * N_ * 4;
    float* eqr = (float*)(ws + off);  off += (size_t)B_ * N_ * 4;
    unsigned int* bits = (unsigned int*)(ws + off); off += (size_t)N_ * 64 * 4; // 512 KB

    k_emb<<<dim3(N_ / 64, B_), 256, 0, stream>>>(x, W, adj, be, wq, bq, wk, bk,
                                                 Pb, qa, ka, Eq, eqs, Ek, eks,
                                                 bits, denom);
    k_denom<<<dim3(8, 16, 8), 256, 0, stream>>>(bits, qa, ka, Eq, eqs, Ek, eks, denom);
    k_post<<<B_ * N_ / 256, 256, 0, stream>>>(denom, Eq, eqs, rd, Eqr, eqr);
    k_attn<<<dim3(N_ / 32, B_), 256, 0, stream>>>(Ek, eks, rd, Eqr, eqr, bits, Pb, out);
}